// Round 10
// baseline (457.117 us; speedup 1.0000x reference)
//
#include <hip/hip_runtime.h>
#include <math.h>

#define D 128
#define LN_EPS 1e-5f

#define NB_SHIFT 7                   // 128 nodes per bucket
#define BIN_EPT 16                   // edges per thread in hist/bin passes
#define BIN_CHUNK (BIN_EPT * 256)    // 4096 edges per block
#define TS 136                       // out-tile stride (ushorts): rows 16B-aligned

typedef unsigned short ushort_t;
typedef unsigned int uint_t;
typedef unsigned char uchar_t;
typedef __attribute__((ext_vector_type(8))) short bf16x8;
typedef __attribute__((ext_vector_type(8))) unsigned short u16x8;
typedef __attribute__((ext_vector_type(4))) float f32x4;
typedef __attribute__((ext_vector_type(2))) float f32x2;
typedef __attribute__((ext_vector_type(2))) unsigned int uintx2;

static __device__ __forceinline__ float bf2f(ushort_t u) {
    union { uint_t i; float f; } c; c.i = ((uint_t)u) << 16; return c.f;
}
static __device__ __forceinline__ ushort_t f2bf(float f) {
    union { float f; uint_t i; } c; c.f = f;
    uint_t u = c.i;
    uint_t r = (u + 0x7fffu + ((u >> 16) & 1u)) >> 16;   // RNE
    return (ushort_t)r;
}

// decode 8 fp8-e4m3 (two dwords), packed f32x2 accumulate (8 VALU / vector)
static __device__ __forceinline__ void acc8_pk(f32x2* __restrict__ a, uintx2 v) {
    a[0] += __builtin_amdgcn_cvt_pk_f32_fp8((int)v[0], false);
    a[1] += __builtin_amdgcn_cvt_pk_f32_fp8((int)v[0], true);
    a[2] += __builtin_amdgcn_cvt_pk_f32_fp8((int)v[1], false);
    a[3] += __builtin_amdgcn_cvt_pk_f32_fp8((int)v[1], true);
}

// cast 2048 fp32 -> bf16, dense row-major (weights). NT on single-use reads.
static __device__ __forceinline__ void cast_block(const float* __restrict__ in,
                                                  ushort_t* __restrict__ outp,
                                                  int rel, int tid) {
    int i = (rel * 256 + tid) * 8;
    f32x4 a = __builtin_nontemporal_load((const f32x4*)&in[i]);
    f32x4 c = __builtin_nontemporal_load((const f32x4*)&in[i + 4]);
    u16x8 v;
    v[0] = f2bf(a.x); v[1] = f2bf(a.y); v[2] = f2bf(a.z); v[3] = f2bf(a.w);
    v[4] = f2bf(c.x); v[5] = f2bf(c.y); v[6] = f2bf(c.z); v[7] = f2bf(c.w);
    *(u16x8*)&outp[i] = v;
}

// cast 2048 fp32 -> bf16 AND fp8-e4m3 (x: gather table copy). fp8 rows are
// 128 B (2 lines/edge) and the 12.8 MB table roughly doubles L2 hit rate —
// this took hbm_bytes 218->135 MB (R4).
static __device__ __forceinline__ void cast_block_x8(const float* __restrict__ in,
                                                     ushort_t* __restrict__ obf,
                                                     uchar_t* __restrict__ of8,
                                                     int rel, int tid) {
    int i = (rel * 256 + tid) * 8;
    f32x4 a = __builtin_nontemporal_load((const f32x4*)&in[i]);
    f32x4 c = __builtin_nontemporal_load((const f32x4*)&in[i + 4]);
    u16x8 v;
    v[0] = f2bf(a.x); v[1] = f2bf(a.y); v[2] = f2bf(a.z); v[3] = f2bf(a.w);
    v[4] = f2bf(c.x); v[5] = f2bf(c.y); v[6] = f2bf(c.z); v[7] = f2bf(c.w);
    *(u16x8*)&obf[i] = v;
    int d0 = __builtin_amdgcn_cvt_pk_fp8_f32(a.x, a.y, 0, false);
    d0 = __builtin_amdgcn_cvt_pk_fp8_f32(a.z, a.w, d0, true);
    int d1 = __builtin_amdgcn_cvt_pk_fp8_f32(c.x, c.y, 0, false);
    d1 = __builtin_amdgcn_cvt_pk_fp8_f32(c.z, c.w, d1, true);
    uintx2 o; o[0] = (uint_t)d0; o[1] = (uint_t)d1;
    *(uintx2*)&of8[i] = o;
}

// ---------------- prep: weight casts + per-node degree histogram -------------
// R10: degree via fire-and-forget global atomicAdd (no return value -> no
// round-trip). Replaces the bucket-level LDS hist; feeds the direct-to-CSR
// chain that eliminates the pairs array + bucket_csr pass (~25 MB + 1 dispatch).
__global__ __launch_bounds__(256) void prep_kernel(
    const float* __restrict__ wl, ushort_t* __restrict__ wl_bf,
    const float* __restrict__ wr, ushort_t* __restrict__ wr_bf,
    const float* __restrict__ w1, ushort_t* __restrict__ w1_bf,
    const int* __restrict__ ei, int E, int* __restrict__ deg,
    int bwl, int bwr, int bw1) {
    const int b = blockIdx.x;
    const int tid = threadIdx.x;

    if (b < bw1) {
        if (b < bwl)      cast_block(wl, wl_bf, b, tid);
        else if (b < bwr) cast_block(wr, wr_bf, b - bwl, tid);
        else              cast_block(w1, w1_bf, b - bwr, tid);
        return;
    }

    int e0 = (b - bw1) * BIN_CHUNK;
    #pragma unroll
    for (int i = 0; i < BIN_EPT; ++i) {
        int e = e0 + i * 256 + tid;
        if (e < E) atomicAdd(&deg[ei[E + e]], 1);
    }
}

// ---------------- bucket sums from deg (782 blocks, tiny) --------------------
__global__ __launch_bounds__(256) void bucket_sum_kernel(const int* __restrict__ deg,
                                                         int* __restrict__ bcnt, int n) {
    __shared__ int ws[4];
    const int b = blockIdx.x;
    const int tid = threadIdx.x;
    int node = (b << NB_SHIFT) + tid;
    int v = (tid < 128 && node < n) ? deg[node] : 0;
    #pragma unroll
    for (int off = 1; off < 64; off <<= 1) v += __shfl_xor(v, off, 64);
    if ((tid & 63) == 0) ws[tid >> 6] = v;
    __syncthreads();
    if (tid == 0) bcnt[b] = ws[0] + ws[1] + ws[2] + ws[3];
}

__global__ __launch_bounds__(1024) void scan_buckets_kernel(const int* __restrict__ bcnt,
                                                            int* __restrict__ bptr,
                                                            int* __restrict__ bcur, int nb) {
    __shared__ int wt[16];
    const int lane = threadIdx.x & 63;
    const int wid = threadIdx.x >> 6;
    int running = 0;
    for (int base = 0; base < nb; base += 1024) {
        int i = base + (int)threadIdx.x;
        int v = (i < nb) ? bcnt[i] : 0;
        int incl = v;
        #pragma unroll
        for (int off = 1; off < 64; off <<= 1) {
            int t = __shfl_up(incl, off, 64);
            if (lane >= off) incl += t;
        }
        if (lane == 63) wt[wid] = incl;
        __syncthreads();
        int prefix = running;
        for (int w = 0; w < wid; ++w) prefix += wt[w];
        if (i < nb) {
            int ex = prefix + incl - v;
            bptr[i] = ex;
            bcur[i] = ex;
        }
        int total = 0;
        for (int w = 0; w < 16; ++w) total += wt[w];
        __syncthreads();
        running += total;
    }
    if (threadIdx.x == 0) bptr[nb] = running;
}

// ---------------- per-node row_ptr + atomic cursors (782 blocks, tiny) -------
__global__ __launch_bounds__(256) void node_ptr_kernel(
    const int* __restrict__ deg, const int* __restrict__ bptr,
    int* __restrict__ row_ptr, int* __restrict__ cur, int nb, int n) {
    __shared__ int wtot[4];
    const int b = blockIdx.x;
    const int tid = threadIdx.x;
    int node = (b << NB_SHIFT) + tid;
    int v = (tid < 128 && node < n) ? deg[node] : 0;
    int lane = tid & 63, wv = tid >> 6;
    int incl = v;
    #pragma unroll
    for (int off = 1; off < 64; off <<= 1) {
        int t = __shfl_up(incl, off, 64);
        if (lane >= off) incl += t;
    }
    if (lane == 63) wtot[wv] = incl;
    __syncthreads();
    if (tid < 128 && node < n) {
        int excl = incl - v + ((wv == 1) ? wtot[0] : 0);
        int rp = bptr[b] + excl;
        row_ptr[node] = rp;
        cur[node] = rp;
    }
    if (b == nb - 1 && tid == 0) row_ptr[n] = bptr[nb];
}

// ---------------- bin pass + x cast fused: DIRECT-to-CSR ---------------------
// [0,bx) cast x | [bx,...) pos = atomicAdd(cur[dst]) -> csr_src[pos] = src.
// One scatter pass (was two: pairs then bucket_csr). cur is a 400 KB hot
// array; ~16 increments/counter -> benign contention.
__global__ __launch_bounds__(256) void bin_edges_kernel(
    const float* __restrict__ x, ushort_t* __restrict__ x_bf, uchar_t* __restrict__ x_f8,
    const int* __restrict__ ei, int E,
    int* __restrict__ cur, int* __restrict__ csr_src, int bx) {
    const int b = blockIdx.x;
    const int tid = threadIdx.x;

    if (b < bx) { cast_block_x8(x, x_bf, x_f8, b, tid); return; }

    int e0 = (b - bx) * BIN_CHUNK;
    int s_r[BIN_EPT], d_r[BIN_EPT], p_r[BIN_EPT];
    #pragma unroll
    for (int i = 0; i < BIN_EPT; ++i) {
        int e = e0 + i * 256 + tid;
        if (e < E) { s_r[i] = ei[e]; d_r[i] = ei[E + e]; } else d_r[i] = -1;
    }
    #pragma unroll
    for (int i = 0; i < BIN_EPT; ++i)
        if (d_r[i] >= 0) p_r[i] = atomicAdd(&cur[d_r[i]], 1);
    #pragma unroll
    for (int i = 0; i < BIN_EPT; ++i)
        if (d_r[i] >= 0) csr_src[p_r[i]] = s_r[i];
}

// ---------------- fused SAGE layer: fp8 gather-agg -> LDS -> MFMA -> LN+SiLU --
// Phase B = R6's proven structure (88.6 us/layer): flat per-node lists, 2-node
// pairs, 8-deep batches (16 row loads in flight/wave), packed f32x2 accumulate.
// do_head (verified R8/R9): fuse MLP head reading the output tile from LDS —
// h2 never touches global (saves 51 MB round-trip + one dispatch).
// BYTE-IDENTICAL to R9's kernel.
__global__ __launch_bounds__(256, 5) void sage_fused(
    const ushort_t* __restrict__ hprev, const uchar_t* __restrict__ hq8,
    const int* __restrict__ row_ptr, const int* __restrict__ csr_src,
    const ushort_t* __restrict__ Wl, const ushort_t* __restrict__ Wr,
    const float* __restrict__ bl, const float* __restrict__ br,
    const float* __restrict__ lng, const float* __restrict__ lnb,
    ushort_t* __restrict__ hout, uchar_t* __restrict__ hf8, int wf8,
    const ushort_t* __restrict__ W1h, const float* __restrict__ b1h,
    const float* __restrict__ w2h, const float* __restrict__ b2h,
    float* __restrict__ outp, int do_head, int n) {
    __shared__ ushort_t stage[16384];          // 32768 B total
    ushort_t* tile = stage;                                        // 64 x TS, 17408 B
    float (*part_s)[4]  = (float(*)[4])((char*)stage + 17408);     // 1 KB
    float (*part_s2)[4] = (float(*)[4])((char*)stage + 18432);     // 1 KB

    const int tid = threadIdx.x;
    const int w = tid >> 6;
    const int lane = tid & 63;
    const int quad = lane >> 4;
    const int l16 = lane & 15;
    const int n0 = blockIdx.x * 64;

    // phase A: stage own hin rows into upper half (chunk-XOR swizzle)
    #pragma unroll
    for (int i = 0; i < 4; ++i) {
        int g = i * 256 + tid;
        int row = g >> 4, ch = g & 15;
        int gr = n0 + row; if (gr >= n) gr = n - 1;
        u16x8 v = *(const u16x8*)&hprev[(size_t)gr * D + ch * 8];
        *(u16x8*)&stage[8192 + row * 128 + (ch ^ (row & 7)) * 8] = v;
    }

    // phase B: fp8 aggregation, 2-node pairs, 8-deep batches (16 in flight)
    const int G = tid >> 4;
    const uchar_t* __restrict__ hq8l = hq8 + l16 * 8;
    #pragma unroll
    for (int kp = 0; kp < 2; ++kp) {
        int rowA = G * 4 + kp * 2;
        int rowB = rowA + 1;
        int nodeA = n0 + rowA;
        int nodeB = n0 + rowB;
        f32x2 aA[4], aB[4];
        #pragma unroll
        for (int i = 0; i < 4; ++i) { aA[i] = (f32x2){0.f, 0.f}; aB[i] = (f32x2){0.f, 0.f}; }
        int eA = 0, s1A = 0, eB = 0, s1B = 0, dgA = 0, dgB = 0;
        if (nodeA < n) { eA = row_ptr[nodeA]; s1A = row_ptr[nodeA + 1]; dgA = s1A - eA; }
        if (nodeB < n) { eB = row_ptr[nodeB]; s1B = row_ptr[nodeB + 1]; dgB = s1B - eB; }
        while (eA + 8 <= s1A && eB + 8 <= s1B) {
            int ia[8], ib[8];
            #pragma unroll
            for (int j = 0; j < 8; ++j) { ia[j] = csr_src[eA + j]; ib[j] = csr_src[eB + j]; }
            uintx2 va[8], vb[8];
            #pragma unroll
            for (int j = 0; j < 8; ++j)
                va[j] = *(const uintx2*)&hq8l[(size_t)ia[j] * D];
            #pragma unroll
            for (int j = 0; j < 8; ++j)
                vb[j] = *(const uintx2*)&hq8l[(size_t)ib[j] * D];
            #pragma unroll
            for (int j = 0; j < 8; ++j) { acc8_pk(aA, va[j]); acc8_pk(aB, vb[j]); }
            eA += 8; eB += 8;
        }
        for (; eA + 4 <= s1A; eA += 4) {
            int ia[4];
            #pragma unroll
            for (int j = 0; j < 4; ++j) ia[j] = csr_src[eA + j];
            uintx2 va[4];
            #pragma unroll
            for (int j = 0; j < 4; ++j)
                va[j] = *(const uintx2*)&hq8l[(size_t)ia[j] * D];
            #pragma unroll
            for (int j = 0; j < 4; ++j) acc8_pk(aA, va[j]);
        }
        for (; eA < s1A; ++eA) {
            uintx2 vv = *(const uintx2*)&hq8l[(size_t)csr_src[eA] * D];
            acc8_pk(aA, vv);
        }
        for (; eB + 4 <= s1B; eB += 4) {
            int ib[4];
            #pragma unroll
            for (int j = 0; j < 4; ++j) ib[j] = csr_src[eB + j];
            uintx2 vb[4];
            #pragma unroll
            for (int j = 0; j < 4; ++j)
                vb[j] = *(const uintx2*)&hq8l[(size_t)ib[j] * D];
            #pragma unroll
            for (int j = 0; j < 4; ++j) acc8_pk(aB, vb[j]);
        }
        for (; eB < s1B; ++eB) {
            uintx2 vv = *(const uintx2*)&hq8l[(size_t)csr_src[eB] * D];
            acc8_pk(aB, vv);
        }
        float scA = (dgA > 0) ? (1.0f / (float)dgA) : 0.0f;
        float scB = (dgB > 0) ? (1.0f / (float)dgB) : 0.0f;
        u16x8 oA, oB;
        #pragma unroll
        for (int i = 0; i < 8; ++i) {
            oA[i] = f2bf(aA[i >> 1][i & 1] * scA);
            oB[i] = f2bf(aB[i >> 1][i & 1] * scB);
        }
        *(u16x8*)&stage[rowA * 128 + (l16 ^ (rowA & 7)) * 8] = oA;
        *(u16x8*)&stage[rowB * 128 + (l16 ^ (rowB & 7)) * 8] = oB;
    }
    __syncthreads();

    // phase C: main K=256 MFMA (A from LDS, B from global/L2)
    f32x4 acc[4][2];
    #pragma unroll
    for (int rt = 0; rt < 4; ++rt)
        #pragma unroll
        for (int jl = 0; jl < 2; ++jl) acc[rt][jl] = (f32x4){0.f, 0.f, 0.f, 0.f};

    #pragma unroll
    for (int c = 0; c < 8; ++c) {
        const ushort_t* __restrict__ W = (c < 4) ? Wl : Wr;
        const int kb = (c & 3) * 32;
        const ushort_t* sbase = &stage[(c < 4) ? 0 : 8192];
        const int cl = (c & 3) * 4 + quad;
        bf16x8 bfr[2];
        #pragma unroll
        for (int jl = 0; jl < 2; ++jl) {
            int j = (2 * w + jl) * 16 + l16;
            bfr[jl] = *(const bf16x8*)&W[(size_t)j * D + kb + quad * 8];
        }
        bf16x8 af[4];
        #pragma unroll
        for (int rt = 0; rt < 4; ++rt) {
            int row = rt * 16 + l16;
            af[rt] = *(const bf16x8*)&sbase[row * 128 + ((cl ^ (l16 & 7)) * 8)];
        }
        #pragma unroll
        for (int rt = 0; rt < 4; ++rt)
            #pragma unroll
            for (int jl = 0; jl < 2; ++jl)
                acc[rt][jl] = __builtin_amdgcn_mfma_f32_16x16x32_bf16(af[rt], bfr[jl],
                                                                      acc[rt][jl], 0, 0, 0);
    }
    __syncthreads();   // stage reads done; overlays become writable

    // phase D: bias + cross-wave LN partials
    float bsum[2], g[2], bb[2];
    #pragma unroll
    for (int jl = 0; jl < 2; ++jl) {
        int j = (2 * w + jl) * 16 + l16;
        bsum[jl] = bl[j] + br[j];
        g[jl] = lng[j];
        bb[jl] = lnb[j];
    }
    #pragma unroll
    for (int rt = 0; rt < 4; ++rt) {
        #pragma unroll
        for (int r = 0; r < 4; ++r) {
            float v0 = acc[rt][0][r] + bsum[0];
            float v1 = acc[rt][1][r] + bsum[1];
            acc[rt][0][r] = v0;
            acc[rt][1][r] = v1;
            float s = v0 + v1;
            float s2 = v0 * v0 + v1 * v1;
            #pragma unroll
            for (int off = 1; off < 16; off <<= 1) {
                s += __shfl_xor(s, off, 64);
                s2 += __shfl_xor(s2, off, 64);
            }
            if (l16 == 0) {
                int row = rt * 16 + quad * 4 + r;
                part_s[row][w] = s;
                part_s2[row][w] = s2;
            }
        }
    }
    __syncthreads();

    // finish LN + SiLU, write bf16 out-tile
    #pragma unroll
    for (int rt = 0; rt < 4; ++rt) {
        #pragma unroll
        for (int r = 0; r < 4; ++r) {
            int row = rt * 16 + quad * 4 + r;
            float s = part_s[row][0] + part_s[row][1] + part_s[row][2] + part_s[row][3];
            float s2 = part_s2[row][0] + part_s2[row][1] + part_s2[row][2] + part_s2[row][3];
            float mean = s * (1.0f / 128.0f);
            float var = s2 * (1.0f / 128.0f) - mean * mean;
            float rstd = rsqrtf(var + LN_EPS);
            #pragma unroll
            for (int jl = 0; jl < 2; ++jl) {
                float z = (acc[rt][jl][r] - mean) * rstd * g[jl] + bb[jl];
                float sv = z / (1.0f + expf(-z));
                tile[row * TS + (2 * w + jl) * 16 + l16] = f2bf(sv);
            }
        }
    }
    __syncthreads();

    if (!do_head) {
        int row = tid >> 2, seg = tid & 3;
        int node = n0 + row;
        if (node < n) {
            #pragma unroll
            for (int k2 = 0; k2 < 4; ++k2) {
                u16x8 vv = *(const u16x8*)&tile[row * TS + seg * 32 + k2 * 8];
                *(u16x8*)&hout[(size_t)node * D + seg * 32 + k2 * 8] = vv;
                if (wf8) {
                    int d0 = __builtin_amdgcn_cvt_pk_fp8_f32(bf2f(vv[0]), bf2f(vv[1]), 0, false);
                    d0 = __builtin_amdgcn_cvt_pk_fp8_f32(bf2f(vv[2]), bf2f(vv[3]), d0, true);
                    int d1 = __builtin_amdgcn_cvt_pk_fp8_f32(bf2f(vv[4]), bf2f(vv[5]), 0, false);
                    d1 = __builtin_amdgcn_cvt_pk_fp8_f32(bf2f(vv[6]), bf2f(vv[7]), d1, true);
                    uintx2 o; o[0] = (uint_t)d0; o[1] = (uint_t)d1;
                    *(uintx2*)&hf8[(size_t)node * D + seg * 32 + k2 * 8] = o;
                }
            }
        }
    } else {
        // phase E: fused MLP head — A-tile from LDS (tile, linear TS layout)
        #pragma unroll
        for (int rt = 0; rt < 4; ++rt)
            #pragma unroll
            for (int jl = 0; jl < 2; ++jl) acc[rt][jl] = (f32x4){0.f, 0.f, 0.f, 0.f};
        #pragma unroll
        for (int c = 0; c < 4; ++c) {
            const int kb = c * 32;
            bf16x8 bfr[2];
            #pragma unroll
            for (int jl = 0; jl < 2; ++jl) {
                int j = (2 * w + jl) * 16 + l16;
                bfr[jl] = *(const bf16x8*)&W1h[(size_t)j * D + kb + quad * 8];
            }
            bf16x8 af[4];
            #pragma unroll
            for (int rt = 0; rt < 4; ++rt) {
                int row = rt * 16 + l16;
                af[rt] = *(const bf16x8*)&tile[row * TS + kb + quad * 8];
            }
            #pragma unroll
            for (int rt = 0; rt < 4; ++rt)
                #pragma unroll
                for (int jl = 0; jl < 2; ++jl)
                    acc[rt][jl] = __builtin_amdgcn_mfma_f32_16x16x32_bf16(af[rt], bfr[jl],
                                                                          acc[rt][jl], 0, 0, 0);
        }
        float bias1[2], wv2[2];
        #pragma unroll
        for (int jl = 0; jl < 2; ++jl) {
            int j = (2 * w + jl) * 16 + l16;
            bias1[jl] = b1h[j];
            wv2[jl] = w2h[j];
        }
        __syncthreads();   // tile reads done; part_s reusable
        #pragma unroll
        for (int rt = 0; rt < 4; ++rt) {
            #pragma unroll
            for (int r = 0; r < 4; ++r) {
                float p = fmaxf(acc[rt][0][r] + bias1[0], 0.0f) * wv2[0]
                        + fmaxf(acc[rt][1][r] + bias1[1], 0.0f) * wv2[1];
                #pragma unroll
                for (int off = 1; off < 16; off <<= 1) p += __shfl_xor(p, off, 64);
                if (l16 == 0) part_s[rt * 16 + quad * 4 + r][w] = p;
            }
        }
        __syncthreads();
        if (tid < 64) {
            int node = n0 + tid;
            if (node < n)
                outp[node] = part_s[tid][0] + part_s[tid][1] + part_s[tid][2]
                           + part_s[tid][3] + b2h[0];
        }
    }
}

// ---------------- launch ----------------
static inline size_t align_up(size_t v, size_t a) { return (v + a - 1) & ~(a - 1); }

extern "C" void kernel_launch(void* const* d_in, const int* in_sizes, int n_in,
                              void* d_out, int out_size, void* d_ws, size_t ws_size,
                              hipStream_t stream) {
    const float* x       = (const float*)d_in[0];
    const int*   ei      = (const int*)d_in[1];
    const float* lin_l_w = (const float*)d_in[2];
    const float* lin_l_b = (const float*)d_in[3];
    const float* lin_r_w = (const float*)d_in[4];
    const float* lin_r_b = (const float*)d_in[5];
    const float* ln_g    = (const float*)d_in[6];
    const float* ln_b    = (const float*)d_in[7];
    const float* mlp_w1  = (const float*)d_in[8];
    const float* mlp_b1  = (const float*)d_in[9];
    const float* mlp_w2  = (const float*)d_in[10];
    const float* mlp_b2  = (const float*)d_in[11];
    float* out = (float*)d_out;

    const int N = in_sizes[0] / D;   // 100000
    const int E = in_sizes[1] / 2;   // 1600000
    const int NB = (N + (1 << NB_SHIFT) - 1) >> NB_SHIFT;   // 782

    // workspace layout
    char* w = (char*)d_ws;
    size_t off = 0;
    int* bcnt = (int*)(w + off);       off = align_up(off + sizeof(int) * (size_t)(NB + 1), 512);
    int* bptr = (int*)(w + off);       off = align_up(off + sizeof(int) * (size_t)(NB + 1), 512);
    int* bcur = (int*)(w + off);       off = align_up(off + sizeof(int) * (size_t)(NB + 1), 512);
    int* deg = (int*)(w + off);        off = align_up(off + sizeof(int) * (size_t)N, 512);
    int* cur = (int*)(w + off);        off = align_up(off + sizeof(int) * (size_t)N, 512);
    int* row_ptr = (int*)(w + off);    off = align_up(off + sizeof(int) * (size_t)(N + 1), 512);
    int* csr_src = (int*)(w + off);    off = align_up(off + sizeof(int) * (size_t)E, 512);
    ushort_t* x_bf = (ushort_t*)(w + off);   off = align_up(off + 2ull * N * D, 512);
    ushort_t* h1_bf = (ushort_t*)(w + off);  off = align_up(off + 2ull * N * D, 512);
    uchar_t* x_f8  = (uchar_t*)(w + off);    off = align_up(off + 1ull * N * D, 512);
    uchar_t* h1_f8 = (uchar_t*)(w + off);    off = align_up(off + 1ull * N * D, 512);
    ushort_t* wl_bf = (ushort_t*)(w + off);  off = align_up(off + 2ull * 2 * D * D, 512);
    ushort_t* wr_bf = (ushort_t*)(w + off);  off = align_up(off + 2ull * 2 * D * D, 512);
    ushort_t* w1_bf = (ushort_t*)(w + off);  off = align_up(off + 2ull * D * D, 512);

    hipMemsetAsync(deg, 0, sizeof(int) * (size_t)N, stream);

    // prep: weight casts + per-node degree atomics (one launch)
    const int bwl = (2 * D * D) / 2048;          // 16
    const int bwr = bwl + (2 * D * D) / 2048;    // 32
    const int bw1 = bwr + (D * D) / 2048;        // 40
    const int bin_grid = (E + BIN_CHUNK - 1) / BIN_CHUNK;   // 391
    prep_kernel<<<bw1 + bin_grid, 256, 0, stream>>>(
        lin_l_w, wl_bf, lin_r_w, wr_bf, mlp_w1, w1_bf, ei, E, deg, bwl, bwr, bw1);

    // bucket sums -> bucket scan -> per-node row_ptr + cursors (all tiny)
    bucket_sum_kernel<<<NB, 256, 0, stream>>>(deg, bcnt, N);
    scan_buckets_kernel<<<1, 1024, 0, stream>>>(bcnt, bptr, bcur, NB);
    node_ptr_kernel<<<NB, 256, 0, stream>>>(deg, bptr, row_ptr, cur, NB, N);

    // bin pass + x cast fused: direct-to-CSR single scatter
    const int bx = (N * D) / 2048;               // 6250
    bin_edges_kernel<<<bx + bin_grid, 256, 0, stream>>>(
        x, x_bf, x_f8, ei, E, cur, csr_src, bx);

    const int gemm_grid = (N + 63) / 64;

    // layer 0 (fp8 gather; also emits h1 fp8 copy for layer 1's gather)
    sage_fused<<<gemm_grid, 256, 0, stream>>>(
        x_bf, x_f8, row_ptr, csr_src, wl_bf, wr_bf, lin_l_b, lin_r_b, ln_g, ln_b,
        h1_bf, h1_f8, 1, nullptr, nullptr, nullptr, nullptr, nullptr, 0, N);
    // layer 1 + fused MLP head (h2 never leaves LDS)
    sage_fused<<<gemm_grid, 256, 0, stream>>>(
        h1_bf, h1_f8, row_ptr, csr_src, wl_bf + D * D, wr_bf + D * D, lin_l_b + D,
        lin_r_b + D, ln_g + D, ln_b + D, h1_bf, h1_f8, 0,
        w1_bf, mlp_b1, mlp_w2, mlp_b2, out, 1, N);
}

// Round 11
// 334.012 us; speedup vs baseline: 1.3686x; 1.3686x over previous
//
#include <hip/hip_runtime.h>
#include <math.h>

#define D 128
#define LN_EPS 1e-5f

#define NB_SHIFT 7                   // 128 nodes per bucket
#define BIN_EPT 16                   // edges per thread in hist/bin passes
#define BIN_CHUNK (BIN_EPT * 256)    // 4096 edges per block
#define MAXB 800                     // >= NB (782)
#define SRC_BITS 25                  // pack: (dloc << 25) | src  (src < 2^25)
#define TS 136                       // out-tile stride (ushorts): rows 16B-aligned

typedef unsigned short ushort_t;
typedef unsigned int uint_t;
typedef unsigned char uchar_t;
typedef __attribute__((ext_vector_type(8))) short bf16x8;
typedef __attribute__((ext_vector_type(8))) unsigned short u16x8;
typedef __attribute__((ext_vector_type(4))) float f32x4;
typedef __attribute__((ext_vector_type(2))) float f32x2;
typedef __attribute__((ext_vector_type(2))) unsigned int uintx2;

static __device__ __forceinline__ float bf2f(ushort_t u) {
    union { uint_t i; float f; } c; c.i = ((uint_t)u) << 16; return c.f;
}
static __device__ __forceinline__ ushort_t f2bf(float f) {
    union { float f; uint_t i; } c; c.f = f;
    uint_t u = c.i;
    uint_t r = (u + 0x7fffu + ((u >> 16) & 1u)) >> 16;   // RNE
    return (ushort_t)r;
}

// decode 8 fp8-e4m3 (two dwords), packed f32x2 accumulate (8 VALU / vector)
static __device__ __forceinline__ void acc8_pk(f32x2* __restrict__ a, uintx2 v) {
    a[0] += __builtin_amdgcn_cvt_pk_f32_fp8((int)v[0], false);
    a[1] += __builtin_amdgcn_cvt_pk_f32_fp8((int)v[0], true);
    a[2] += __builtin_amdgcn_cvt_pk_f32_fp8((int)v[1], false);
    a[3] += __builtin_amdgcn_cvt_pk_f32_fp8((int)v[1], true);
}

// cast 2048 fp32 -> bf16, dense row-major (weights). NT on single-use reads.
static __device__ __forceinline__ void cast_block(const float* __restrict__ in,
                                                  ushort_t* __restrict__ outp,
                                                  int rel, int tid) {
    int i = (rel * 256 + tid) * 8;
    f32x4 a = __builtin_nontemporal_load((const f32x4*)&in[i]);
    f32x4 c = __builtin_nontemporal_load((const f32x4*)&in[i + 4]);
    u16x8 v;
    v[0] = f2bf(a.x); v[1] = f2bf(a.y); v[2] = f2bf(a.z); v[3] = f2bf(a.w);
    v[4] = f2bf(c.x); v[5] = f2bf(c.y); v[6] = f2bf(c.z); v[7] = f2bf(c.w);
    *(u16x8*)&outp[i] = v;
}

// cast 2048 fp32 -> bf16 AND fp8-e4m3 (x: gather table copy). fp8 rows are
// 128 B (2 lines/edge) and the 12.8 MB table roughly doubles L2 hit rate —
// this took hbm_bytes 218->135 MB (R4).
static __device__ __forceinline__ void cast_block_x8(const float* __restrict__ in,
                                                     ushort_t* __restrict__ obf,
                                                     uchar_t* __restrict__ of8,
                                                     int rel, int tid) {
    int i = (rel * 256 + tid) * 8;
    f32x4 a = __builtin_nontemporal_load((const f32x4*)&in[i]);
    f32x4 c = __builtin_nontemporal_load((const f32x4*)&in[i + 4]);
    u16x8 v;
    v[0] = f2bf(a.x); v[1] = f2bf(a.y); v[2] = f2bf(a.z); v[3] = f2bf(a.w);
    v[4] = f2bf(c.x); v[5] = f2bf(c.y); v[6] = f2bf(c.z); v[7] = f2bf(c.w);
    *(u16x8*)&obf[i] = v;
    int d0 = __builtin_amdgcn_cvt_pk_fp8_f32(a.x, a.y, 0, false);
    d0 = __builtin_amdgcn_cvt_pk_fp8_f32(a.z, a.w, d0, true);
    int d1 = __builtin_amdgcn_cvt_pk_fp8_f32(c.x, c.y, 0, false);
    d1 = __builtin_amdgcn_cvt_pk_fp8_f32(c.z, c.w, d1, true);
    uintx2 o; o[0] = (uint_t)d0; o[1] = (uint_t)d1;
    *(uintx2*)&of8[i] = o;
}

// ---------------- prep: weight casts + HALF the x cast + bucket histogram ----
// R11: the hist dispatch alone was 431 blocks (1.7/CU) — LDS-atomic latency on
// an underfilled machine. Splitting the 6250 x-cast blocks evenly between prep
// and bin_edges fills BOTH dispatches (~13.7 blocks/CU), hiding each one's
// latency-bound phase behind cast streaming. R10's direct-to-CSR is reverted
// (4B random scatter -> 64B write-allocate: WRITE_SIZE 25 -> 148 MB).
// [0,bwl) wl | [bwl,bwr) wr | [bwr,bw1) w1 | [bw1,bw1+bxp) x cast | rest hist
__global__ __launch_bounds__(256) void prep_kernel(
    const float* __restrict__ wl, ushort_t* __restrict__ wl_bf,
    const float* __restrict__ wr, ushort_t* __restrict__ wr_bf,
    const float* __restrict__ w1, ushort_t* __restrict__ w1_bf,
    const float* __restrict__ x, ushort_t* __restrict__ x_bf, uchar_t* __restrict__ x_f8,
    const int* __restrict__ ei, int E, int* __restrict__ bcnt, int nb,
    int bwl, int bwr, int bw1, int bxp) {
    __shared__ int h[MAXB];
    const int b = blockIdx.x;
    const int tid = threadIdx.x;

    if (b < bw1) {
        if (b < bwl)      cast_block(wl, wl_bf, b, tid);
        else if (b < bwr) cast_block(wr, wr_bf, b - bwl, tid);
        else              cast_block(w1, w1_bf, b - bwr, tid);
        return;
    }
    if (b < bw1 + bxp) { cast_block_x8(x, x_bf, x_f8, b - bw1, tid); return; }

    for (int i = tid; i < nb; i += 256) h[i] = 0;
    __syncthreads();
    int e0 = (b - bw1 - bxp) * BIN_CHUNK;
    #pragma unroll
    for (int i = 0; i < BIN_EPT; ++i) {
        int e = e0 + i * 256 + tid;
        if (e < E) atomicAdd(&h[ei[E + e] >> NB_SHIFT], 1);
    }
    __syncthreads();
    for (int i = tid; i < nb; i += 256) {
        int c = h[i];
        if (c) atomicAdd(&bcnt[i], c);
    }
}

__global__ __launch_bounds__(1024) void scan_buckets_kernel(const int* __restrict__ bcnt,
                                                            int* __restrict__ bptr,
                                                            int* __restrict__ bcur, int nb) {
    __shared__ int wt[16];
    const int lane = threadIdx.x & 63;
    const int wid = threadIdx.x >> 6;
    int running = 0;
    for (int base = 0; base < nb; base += 1024) {
        int i = base + (int)threadIdx.x;
        int v = (i < nb) ? bcnt[i] : 0;
        int incl = v;
        #pragma unroll
        for (int off = 1; off < 64; off <<= 1) {
            int t = __shfl_up(incl, off, 64);
            if (lane >= off) incl += t;
        }
        if (lane == 63) wt[wid] = incl;
        __syncthreads();
        int prefix = running;
        for (int w = 0; w < wid; ++w) prefix += wt[w];
        if (i < nb) {
            int ex = prefix + incl - v;
            bptr[i] = ex;
            bcur[i] = ex;
        }
        int total = 0;
        for (int w = 0; w < 16; ++w) total += wt[w];
        __syncthreads();
        running += total;
    }
    if (threadIdx.x == 0) bptr[nb] = running;
}

// ---------------- bin pass + OTHER half of x cast ----------------------------
// [0,bx2) cast x (block rel offset bxp) | [bx2,...) scatter packed pairs
__global__ __launch_bounds__(256) void bin_edges_kernel(
    const float* __restrict__ x, ushort_t* __restrict__ x_bf, uchar_t* __restrict__ x_f8,
    const int* __restrict__ ei, int E,
    int* __restrict__ bcur, uint_t* __restrict__ pairs, int nb, int bx2, int bxp) {
    __shared__ int hist[MAXB];
    __shared__ int base[MAXB];
    const int b = blockIdx.x;
    const int tid = threadIdx.x;

    if (b < bx2) { cast_block_x8(x, x_bf, x_f8, bxp + b, tid); return; }

    for (int i = tid; i < nb; i += 256) hist[i] = 0;
    __syncthreads();

    int e0 = (b - bx2) * BIN_CHUNK;
    int s_r[BIN_EPT], d_r[BIN_EPT], idx_r[BIN_EPT];
    #pragma unroll
    for (int i = 0; i < BIN_EPT; ++i) {
        int e = e0 + i * 256 + tid;
        if (e < E) {
            s_r[i] = ei[e];
            d_r[i] = ei[E + e];
            idx_r[i] = atomicAdd(&hist[d_r[i] >> NB_SHIFT], 1);
        }
    }
    __syncthreads();
    for (int i = tid; i < nb; i += 256) {
        int c = hist[i];
        base[i] = c ? atomicAdd(&bcur[i], c) : 0;
    }
    __syncthreads();
    #pragma unroll
    for (int i = 0; i < BIN_EPT; ++i) {
        int e = e0 + i * 256 + tid;
        if (e < E) {
            int pos = base[d_r[i] >> NB_SHIFT] + idx_r[i];
            pairs[pos] = ((uint_t)(d_r[i] & 127) << SRC_BITS) | (uint_t)s_r[i];
        }
    }
}

__global__ __launch_bounds__(256) void bucket_csr_kernel(const uint_t* __restrict__ pairs,
                                                         const int* __restrict__ bptr,
                                                         int* __restrict__ row_ptr,
                                                         int* __restrict__ csr_src,
                                                         int nb, int n) {
    __shared__ int hist[128];
    __shared__ int cur[128];
    __shared__ int wtot[4];
    const int tid = threadIdx.x;
    const int b = blockIdx.x;
    const int e0 = bptr[b];
    const int e1 = bptr[b + 1];
    const int n0 = b << NB_SHIFT;

    if (tid < 128) hist[tid] = 0;
    __syncthreads();
    for (int e = e0 + tid; e < e1; e += 256)
        atomicAdd(&hist[pairs[e] >> SRC_BITS], 1);
    __syncthreads();

    int v = (tid < 128) ? hist[tid] : 0;
    int lane = tid & 63, wv = tid >> 6;
    int incl = v;
    #pragma unroll
    for (int off = 1; off < 64; off <<= 1) {
        int t = __shfl_up(incl, off, 64);
        if (lane >= off) incl += t;
    }
    if (lane == 63) wtot[wv] = incl;
    __syncthreads();
    if (tid < 128) {
        int excl = incl - v + ((wv == 1) ? wtot[0] : 0);
        cur[tid] = excl;
        int node = n0 + tid;
        if (node < n) row_ptr[node] = e0 + excl;
    }
    if (b == nb - 1 && tid == 0) row_ptr[n] = e1;
    __syncthreads();

    for (int e = e0 + tid; e < e1; e += 256) {
        uint_t p = pairs[e];
        int pos = e0 + atomicAdd(&cur[p >> SRC_BITS], 1);
        csr_src[pos] = (int)(p & ((1u << SRC_BITS) - 1u));
    }
}

// ---------------- fused SAGE layer: fp8 gather-agg -> LDS -> MFMA -> LN+SiLU --
// Phase B = R6's proven structure (88.6 us/layer): flat per-node lists, 2-node
// pairs, 8-deep batches (16 row loads in flight/wave), packed f32x2 accumulate.
// do_head (verified R8/R9): fuse MLP head reading the output tile from LDS —
// h2 never touches global (saves 51 MB round-trip + one dispatch).
// BYTE-IDENTICAL to R9's kernel.
__global__ __launch_bounds__(256, 5) void sage_fused(
    const ushort_t* __restrict__ hprev, const uchar_t* __restrict__ hq8,
    const int* __restrict__ row_ptr, const int* __restrict__ csr_src,
    const ushort_t* __restrict__ Wl, const ushort_t* __restrict__ Wr,
    const float* __restrict__ bl, const float* __restrict__ br,
    const float* __restrict__ lng, const float* __restrict__ lnb,
    ushort_t* __restrict__ hout, uchar_t* __restrict__ hf8, int wf8,
    const ushort_t* __restrict__ W1h, const float* __restrict__ b1h,
    const float* __restrict__ w2h, const float* __restrict__ b2h,
    float* __restrict__ outp, int do_head, int n) {
    __shared__ ushort_t stage[16384];          // 32768 B total
    ushort_t* tile = stage;                                        // 64 x TS, 17408 B
    float (*part_s)[4]  = (float(*)[4])((char*)stage + 17408);     // 1 KB
    float (*part_s2)[4] = (float(*)[4])((char*)stage + 18432);     // 1 KB

    const int tid = threadIdx.x;
    const int w = tid >> 6;
    const int lane = tid & 63;
    const int quad = lane >> 4;
    const int l16 = lane & 15;
    const int n0 = blockIdx.x * 64;

    // phase A: stage own hin rows into upper half (chunk-XOR swizzle)
    #pragma unroll
    for (int i = 0; i < 4; ++i) {
        int g = i * 256 + tid;
        int row = g >> 4, ch = g & 15;
        int gr = n0 + row; if (gr >= n) gr = n - 1;
        u16x8 v = *(const u16x8*)&hprev[(size_t)gr * D + ch * 8];
        *(u16x8*)&stage[8192 + row * 128 + (ch ^ (row & 7)) * 8] = v;
    }

    // phase B: fp8 aggregation, 2-node pairs, 8-deep batches (16 in flight)
    const int G = tid >> 4;
    const uchar_t* __restrict__ hq8l = hq8 + l16 * 8;
    #pragma unroll
    for (int kp = 0; kp < 2; ++kp) {
        int rowA = G * 4 + kp * 2;
        int rowB = rowA + 1;
        int nodeA = n0 + rowA;
        int nodeB = n0 + rowB;
        f32x2 aA[4], aB[4];
        #pragma unroll
        for (int i = 0; i < 4; ++i) { aA[i] = (f32x2){0.f, 0.f}; aB[i] = (f32x2){0.f, 0.f}; }
        int eA = 0, s1A = 0, eB = 0, s1B = 0, dgA = 0, dgB = 0;
        if (nodeA < n) { eA = row_ptr[nodeA]; s1A = row_ptr[nodeA + 1]; dgA = s1A - eA; }
        if (nodeB < n) { eB = row_ptr[nodeB]; s1B = row_ptr[nodeB + 1]; dgB = s1B - eB; }
        while (eA + 8 <= s1A && eB + 8 <= s1B) {
            int ia[8], ib[8];
            #pragma unroll
            for (int j = 0; j < 8; ++j) { ia[j] = csr_src[eA + j]; ib[j] = csr_src[eB + j]; }
            uintx2 va[8], vb[8];
            #pragma unroll
            for (int j = 0; j < 8; ++j)
                va[j] = *(const uintx2*)&hq8l[(size_t)ia[j] * D];
            #pragma unroll
            for (int j = 0; j < 8; ++j)
                vb[j] = *(const uintx2*)&hq8l[(size_t)ib[j] * D];
            #pragma unroll
            for (int j = 0; j < 8; ++j) { acc8_pk(aA, va[j]); acc8_pk(aB, vb[j]); }
            eA += 8; eB += 8;
        }
        for (; eA + 4 <= s1A; eA += 4) {
            int ia[4];
            #pragma unroll
            for (int j = 0; j < 4; ++j) ia[j] = csr_src[eA + j];
            uintx2 va[4];
            #pragma unroll
            for (int j = 0; j < 4; ++j)
                va[j] = *(const uintx2*)&hq8l[(size_t)ia[j] * D];
            #pragma unroll
            for (int j = 0; j < 4; ++j) acc8_pk(aA, va[j]);
        }
        for (; eA < s1A; ++eA) {
            uintx2 vv = *(const uintx2*)&hq8l[(size_t)csr_src[eA] * D];
            acc8_pk(aA, vv);
        }
        for (; eB + 4 <= s1B; eB += 4) {
            int ib[4];
            #pragma unroll
            for (int j = 0; j < 4; ++j) ib[j] = csr_src[eB + j];
            uintx2 vb[4];
            #pragma unroll
            for (int j = 0; j < 4; ++j)
                vb[j] = *(const uintx2*)&hq8l[(size_t)ib[j] * D];
            #pragma unroll
            for (int j = 0; j < 4; ++j) acc8_pk(aB, vb[j]);
        }
        for (; eB < s1B; ++eB) {
            uintx2 vv = *(const uintx2*)&hq8l[(size_t)csr_src[eB] * D];
            acc8_pk(aB, vv);
        }
        float scA = (dgA > 0) ? (1.0f / (float)dgA) : 0.0f;
        float scB = (dgB > 0) ? (1.0f / (float)dgB) : 0.0f;
        u16x8 oA, oB;
        #pragma unroll
        for (int i = 0; i < 8; ++i) {
            oA[i] = f2bf(aA[i >> 1][i & 1] * scA);
            oB[i] = f2bf(aB[i >> 1][i & 1] * scB);
        }
        *(u16x8*)&stage[rowA * 128 + (l16 ^ (rowA & 7)) * 8] = oA;
        *(u16x8*)&stage[rowB * 128 + (l16 ^ (rowB & 7)) * 8] = oB;
    }
    __syncthreads();

    // phase C: main K=256 MFMA (A from LDS, B from global/L2)
    f32x4 acc[4][2];
    #pragma unroll
    for (int rt = 0; rt < 4; ++rt)
        #pragma unroll
        for (int jl = 0; jl < 2; ++jl) acc[rt][jl] = (f32x4){0.f, 0.f, 0.f, 0.f};

    #pragma unroll
    for (int c = 0; c < 8; ++c) {
        const ushort_t* __restrict__ W = (c < 4) ? Wl : Wr;
        const int kb = (c & 3) * 32;
        const ushort_t* sbase = &stage[(c < 4) ? 0 : 8192];
        const int cl = (c & 3) * 4 + quad;
        bf16x8 bfr[2];
        #pragma unroll
        for (int jl = 0; jl < 2; ++jl) {
            int j = (2 * w + jl) * 16 + l16;
            bfr[jl] = *(const bf16x8*)&W[(size_t)j * D + kb + quad * 8];
        }
        bf16x8 af[4];
        #pragma unroll
        for (int rt = 0; rt < 4; ++rt) {
            int row = rt * 16 + l16;
            af[rt] = *(const bf16x8*)&sbase[row * 128 + ((cl ^ (l16 & 7)) * 8)];
        }
        #pragma unroll
        for (int rt = 0; rt < 4; ++rt)
            #pragma unroll
            for (int jl = 0; jl < 2; ++jl)
                acc[rt][jl] = __builtin_amdgcn_mfma_f32_16x16x32_bf16(af[rt], bfr[jl],
                                                                      acc[rt][jl], 0, 0, 0);
    }
    __syncthreads();   // stage reads done; overlays become writable

    // phase D: bias + cross-wave LN partials
    float bsum[2], g[2], bb[2];
    #pragma unroll
    for (int jl = 0; jl < 2; ++jl) {
        int j = (2 * w + jl) * 16 + l16;
        bsum[jl] = bl[j] + br[j];
        g[jl] = lng[j];
        bb[jl] = lnb[j];
    }
    #pragma unroll
    for (int rt = 0; rt < 4; ++rt) {
        #pragma unroll
        for (int r = 0; r < 4; ++r) {
            float v0 = acc[rt][0][r] + bsum[0];
            float v1 = acc[rt][1][r] + bsum[1];
            acc[rt][0][r] = v0;
            acc[rt][1][r] = v1;
            float s = v0 + v1;
            float s2 = v0 * v0 + v1 * v1;
            #pragma unroll
            for (int off = 1; off < 16; off <<= 1) {
                s += __shfl_xor(s, off, 64);
                s2 += __shfl_xor(s2, off, 64);
            }
            if (l16 == 0) {
                int row = rt * 16 + quad * 4 + r;
                part_s[row][w] = s;
                part_s2[row][w] = s2;
            }
        }
    }
    __syncthreads();

    // finish LN + SiLU, write bf16 out-tile
    #pragma unroll
    for (int rt = 0; rt < 4; ++rt) {
        #pragma unroll
        for (int r = 0; r < 4; ++r) {
            int row = rt * 16 + quad * 4 + r;
            float s = part_s[row][0] + part_s[row][1] + part_s[row][2] + part_s[row][3];
            float s2 = part_s2[row][0] + part_s2[row][1] + part_s2[row][2] + part_s2[row][3];
            float mean = s * (1.0f / 128.0f);
            float var = s2 * (1.0f / 128.0f) - mean * mean;
            float rstd = rsqrtf(var + LN_EPS);
            #pragma unroll
            for (int jl = 0; jl < 2; ++jl) {
                float z = (acc[rt][jl][r] - mean) * rstd * g[jl] + bb[jl];
                float sv = z / (1.0f + expf(-z));
                tile[row * TS + (2 * w + jl) * 16 + l16] = f2bf(sv);
            }
        }
    }
    __syncthreads();

    if (!do_head) {
        int row = tid >> 2, seg = tid & 3;
        int node = n0 + row;
        if (node < n) {
            #pragma unroll
            for (int k2 = 0; k2 < 4; ++k2) {
                u16x8 vv = *(const u16x8*)&tile[row * TS + seg * 32 + k2 * 8];
                *(u16x8*)&hout[(size_t)node * D + seg * 32 + k2 * 8] = vv;
                if (wf8) {
                    int d0 = __builtin_amdgcn_cvt_pk_fp8_f32(bf2f(vv[0]), bf2f(vv[1]), 0, false);
                    d0 = __builtin_amdgcn_cvt_pk_fp8_f32(bf2f(vv[2]), bf2f(vv[3]), d0, true);
                    int d1 = __builtin_amdgcn_cvt_pk_fp8_f32(bf2f(vv[4]), bf2f(vv[5]), 0, false);
                    d1 = __builtin_amdgcn_cvt_pk_fp8_f32(bf2f(vv[6]), bf2f(vv[7]), d1, true);
                    uintx2 o; o[0] = (uint_t)d0; o[1] = (uint_t)d1;
                    *(uintx2*)&hf8[(size_t)node * D + seg * 32 + k2 * 8] = o;
                }
            }
        }
    } else {
        // phase E: fused MLP head — A-tile from LDS (tile, linear TS layout)
        #pragma unroll
        for (int rt = 0; rt < 4; ++rt)
            #pragma unroll
            for (int jl = 0; jl < 2; ++jl) acc[rt][jl] = (f32x4){0.f, 0.f, 0.f, 0.f};
        #pragma unroll
        for (int c = 0; c < 4; ++c) {
            const int kb = c * 32;
            bf16x8 bfr[2];
            #pragma unroll
            for (int jl = 0; jl < 2; ++jl) {
                int j = (2 * w + jl) * 16 + l16;
                bfr[jl] = *(const bf16x8*)&W1h[(size_t)j * D + kb + quad * 8];
            }
            bf16x8 af[4];
            #pragma unroll
            for (int rt = 0; rt < 4; ++rt) {
                int row = rt * 16 + l16;
                af[rt] = *(const bf16x8*)&tile[row * TS + kb + quad * 8];
            }
            #pragma unroll
            for (int rt = 0; rt < 4; ++rt)
                #pragma unroll
                for (int jl = 0; jl < 2; ++jl)
                    acc[rt][jl] = __builtin_amdgcn_mfma_f32_16x16x32_bf16(af[rt], bfr[jl],
                                                                          acc[rt][jl], 0, 0, 0);
        }
        float bias1[2], wv2[2];
        #pragma unroll
        for (int jl = 0; jl < 2; ++jl) {
            int j = (2 * w + jl) * 16 + l16;
            bias1[jl] = b1h[j];
            wv2[jl] = w2h[j];
        }
        __syncthreads();   // tile reads done; part_s reusable
        #pragma unroll
        for (int rt = 0; rt < 4; ++rt) {
            #pragma unroll
            for (int r = 0; r < 4; ++r) {
                float p = fmaxf(acc[rt][0][r] + bias1[0], 0.0f) * wv2[0]
                        + fmaxf(acc[rt][1][r] + bias1[1], 0.0f) * wv2[1];
                #pragma unroll
                for (int off = 1; off < 16; off <<= 1) p += __shfl_xor(p, off, 64);
                if (l16 == 0) part_s[rt * 16 + quad * 4 + r][w] = p;
            }
        }
        __syncthreads();
        if (tid < 64) {
            int node = n0 + tid;
            if (node < n)
                outp[node] = part_s[tid][0] + part_s[tid][1] + part_s[tid][2]
                           + part_s[tid][3] + b2h[0];
        }
    }
}

// ---------------- launch ----------------
static inline size_t align_up(size_t v, size_t a) { return (v + a - 1) & ~(a - 1); }

extern "C" void kernel_launch(void* const* d_in, const int* in_sizes, int n_in,
                              void* d_out, int out_size, void* d_ws, size_t ws_size,
                              hipStream_t stream) {
    const float* x       = (const float*)d_in[0];
    const int*   ei      = (const int*)d_in[1];
    const float* lin_l_w = (const float*)d_in[2];
    const float* lin_l_b = (const float*)d_in[3];
    const float* lin_r_w = (const float*)d_in[4];
    const float* lin_r_b = (const float*)d_in[5];
    const float* ln_g    = (const float*)d_in[6];
    const float* ln_b    = (const float*)d_in[7];
    const float* mlp_w1  = (const float*)d_in[8];
    const float* mlp_b1  = (const float*)d_in[9];
    const float* mlp_w2  = (const float*)d_in[10];
    const float* mlp_b2  = (const float*)d_in[11];
    float* out = (float*)d_out;

    const int N = in_sizes[0] / D;   // 100000
    const int E = in_sizes[1] / 2;   // 1600000
    const int NB = (N + (1 << NB_SHIFT) - 1) >> NB_SHIFT;   // 782

    // workspace layout
    char* w = (char*)d_ws;
    size_t off = 0;
    int* bcnt = (int*)(w + off);       off = align_up(off + sizeof(int) * (size_t)(NB + 1), 512);
    int* bptr = (int*)(w + off);       off = align_up(off + sizeof(int) * (size_t)(NB + 1), 512);
    int* bcur = (int*)(w + off);       off = align_up(off + sizeof(int) * (size_t)(NB + 1), 512);
    int* row_ptr = (int*)(w + off);    off = align_up(off + sizeof(int) * (size_t)(N + 1), 512);
    int* csr_src = (int*)(w + off);    off = align_up(off + sizeof(int) * (size_t)E, 512);
    uint_t* pairs = (uint_t*)(w + off); off = align_up(off + sizeof(uint_t) * (size_t)E, 512);
    ushort_t* x_bf = (ushort_t*)(w + off);   off = align_up(off + 2ull * N * D, 512);
    ushort_t* h1_bf = (ushort_t*)(w + off);  off = align_up(off + 2ull * N * D, 512);
    uchar_t* x_f8  = (uchar_t*)(w + off);    off = align_up(off + 1ull * N * D, 512);
    uchar_t* h1_f8 = (uchar_t*)(w + off);    off = align_up(off + 1ull * N * D, 512);
    ushort_t* wl_bf = (ushort_t*)(w + off);  off = align_up(off + 2ull * 2 * D * D, 512);
    ushort_t* wr_bf = (ushort_t*)(w + off);  off = align_up(off + 2ull * 2 * D * D, 512);
    ushort_t* w1_bf = (ushort_t*)(w + off);  off = align_up(off + 2ull * D * D, 512);

    hipMemsetAsync(bcnt, 0, sizeof(int) * (size_t)(NB + 1), stream);

    // prep: weight casts + half the x cast + bucket histogram (one launch)
    const int bwl = (2 * D * D) / 2048;          // 16
    const int bwr = bwl + (2 * D * D) / 2048;    // 32
    const int bw1 = bwr + (D * D) / 2048;        // 40
    const int bin_grid = (E + BIN_CHUNK - 1) / BIN_CHUNK;   // 391
    const int bx = (N * D) / 2048;               // 6250 x-cast blocks total
    const int bxp = bx / 2;                      // 3125 in prep
    const int bx2 = bx - bxp;                    // 3125 in bin_edges
    prep_kernel<<<bw1 + bxp + bin_grid, 256, 0, stream>>>(
        lin_l_w, wl_bf, lin_r_w, wr_bf, mlp_w1, w1_bf, x, x_bf, x_f8,
        ei, E, bcnt, NB, bwl, bwr, bw1, bxp);

    scan_buckets_kernel<<<1, 1024, 0, stream>>>(bcnt, bptr, bcur, NB);

    // bin pass + other half of the x cast
    bin_edges_kernel<<<bx2 + bin_grid, 256, 0, stream>>>(
        x, x_bf, x_f8, ei, E, bcur, pairs, NB, bx2, bxp);

    bucket_csr_kernel<<<NB, 256, 0, stream>>>(pairs, bptr, row_ptr, csr_src, NB, N);

    const int gemm_grid = (N + 63) / 64;

    // layer 0 (fp8 gather; also emits h1 fp8 copy for layer 1's gather)
    sage_fused<<<gemm_grid, 256, 0, stream>>>(
        x_bf, x_f8, row_ptr, csr_src, wl_bf, wr_bf, lin_l_b, lin_r_b, ln_g, ln_b,
        h1_bf, h1_f8, 1, nullptr, nullptr, nullptr, nullptr, nullptr, 0, N);
    // layer 1 + fused MLP head (h2 never leaves LDS)
    sage_fused<<<gemm_grid, 256, 0, stream>>>(
        h1_bf, h1_f8, row_ptr, csr_src, wl_bf + D * D, wr_bf + D * D, lin_l_b + D,
        lin_r_b + D, ln_g + D, ln_b + D, h1_bf, h1_f8, 0,
        w1_bf, mlp_b1, mlp_w2, mlp_b2, out, 1, N);
}